// Round 5
// baseline (1110.095 us; speedup 1.0000x reference)
//
#include <hip/hip_runtime.h>
#include <hip/hip_bf16.h>
#include <hip/hip_cooperative_groups.h>
#include <cstdint>

// GemmaAttention MI355X — single cooperative kernel (R5):
//   P0 convH+costab | P1 transW | sync | P2 projGEMM(QKV) | sync |
//   P3 transV+rope | sync | P4 stats | sync | P5 merge | sync |
//   P6 weights+PV | sync | P7 WoGEMM
// All inner loops verbatim from the R4 multi-kernel version (passed, absmax 0.0156).

#define BB 2
#define SS 2048
#define HIDD 2048
#define NHH 8
#define HDD 256
#define L2E 1.44269504088896340736f
#define QSCALE 0.0625f  // 1/sqrt(256)

namespace cg = cooperative_groups;

typedef float f32x4 __attribute__((ext_vector_type(4)));
typedef short short8 __attribute__((ext_vector_type(8)));
typedef __bf16 bf16x8 __attribute__((ext_vector_type(8)));
typedef __attribute__((address_space(1))) void gvoid;
typedef __attribute__((address_space(3))) void svoid;

__device__ __forceinline__ ushort f2bf(float f){
  union { float f; uint32_t u; } v; v.f = f;
  uint32_t r = (v.u + 0x7fffu + ((v.u >> 16) & 1u)) >> 16;
  return (ushort)r;
}
__device__ __forceinline__ float bf2f(ushort u){
  union { uint32_t u; float f; } v; v.u = ((uint32_t)u) << 16;
  return v.f;
}
__device__ __forceinline__ void gld_lds16(const ushort* gp, ushort* lp){
  __builtin_amdgcn_global_load_lds((gvoid*)gp, (svoid*)lp, 16, 0, 0);
}
__device__ __forceinline__ f32x4 mfma16(short8 a, short8 b, f32x4 c){
  return __builtin_amdgcn_mfma_f32_16x16x32_bf16(
      __builtin_bit_cast(bf16x8, a), __builtin_bit_cast(bf16x8, b), c, 0, 0, 0);
}

struct KArgs {
  const float* H; const int* pos;
  const float* Wq; const float* Wk; const float* Wv; const float* Wo;
  float* out; float* Wts;
  ushort* Hb; ushort* Wt; ushort* Wot;
  ushort* Qr; ushort* Kr; ushort* Vr; ushort* Vt;
  float2* cst;
  float* mpart; float* lpart; float* mfin; float* invl;
  ushort* Ows;
};

// ---- m97-style 128x128 bf16 GEMM phase (verbatim inner loops) ----
// mode 0: C fp32 -> Cf[row*2048+n]
// mode 1: QKV scatter: n<2048 -> Qr; n<2304 -> Kr; else -> Vr (row-major)
__device__ __forceinline__ void gemm_phase(const ushort* A, const ushort* Bt,
    int nbx, int nTiles, int Ksteps, int mode, float* Cf,
    ushort* Qr, ushort* Kr, ushort* Vr, char* smem,
    int tid, int bid, int nblk){
  ushort* As = (ushort*)smem;
  ushort* Bs = As + 128*32;
  const int l = tid & 63, w = tid >> 6;
  const int lr = l & 15, lg = l >> 4;
  const int wr = (w >> 1) * 64, wc = (w & 1) * 64;
  for (int vt = bid; vt < nTiles; vt += nblk){
    const int m0 = (vt / nbx) * 128, n0 = (vt % nbx) * 128;
    f32x4 acc[4][4] = {};
    for (int kt = 0; kt < Ksteps; ++kt){
      const int kb = kt * 32;
      #pragma unroll
      for (int t = 0; t < 2; ++t){
        int r = t*64 + (tid >> 2), g = tid & 3;
        int gl = g ^ ((r >> 1) & 3);          // 2-way-conflict chunk swizzle
        gld_lds16(A  + (size_t)(m0 + r) * 2048 + kb + gl*8, As + (t*256 + (tid & ~63))*8);
        gld_lds16(Bt + (size_t)(n0 + r) * 2048 + kb + gl*8, Bs + (t*256 + (tid & ~63))*8);
      }
      __syncthreads();
      short8 af[4], bf[4];
      #pragma unroll
      for (int mi = 0; mi < 4; ++mi){
        int r = wr + mi*16 + lr;
        af[mi] = *(const short8*)&As[r*32 + ((lg ^ ((r>>1)&3)) << 3)];
      }
      #pragma unroll
      for (int ni = 0; ni < 4; ++ni){
        int r = wc + ni*16 + lr;
        bf[ni] = *(const short8*)&Bs[r*32 + ((lg ^ ((r>>1)&3)) << 3)];
      }
      #pragma unroll
      for (int mi = 0; mi < 4; ++mi)
        #pragma unroll
        for (int ni = 0; ni < 4; ++ni)
          acc[mi][ni] = mfma16(af[mi], bf[ni], acc[mi][ni]);
      __syncthreads();
    }
    #pragma unroll
    for (int mi = 0; mi < 4; ++mi){
      #pragma unroll
      for (int ni = 0; ni < 4; ++ni){
        #pragma unroll
        for (int r = 0; r < 4; ++r){
          int row = m0 + wr + mi*16 + lg*4 + r;
          int nn  = n0 + wc + ni*16 + lr;
          float v = acc[mi][ni][r];
          if (mode == 0){
            Cf[(size_t)row * 2048 + nn] = v;
          } else {
            if (nn < 2048)      Qr[(size_t)row*2048 + nn] = f2bf(v);
            else if (nn < 2304) Kr[(size_t)row*256 + (nn - 2048)] = f2bf(v);
            else                Vr[(size_t)row*256 + (nn - 2304)] = f2bf(v);
          }
        }
      }
    }
  }
}

__global__ __launch_bounds__(256, 2) void k_fused(KArgs a){
  __shared__ __align__(16) char smem[73728];   // 72 KB -> 2 blocks/CU
  cg::grid_group gg = cg::this_grid();
  const int tid = threadIdx.x;
  const int bid = blockIdx.x, nblk = gridDim.x;
  const int gidx = bid*256 + tid, gthr = nblk*256;
  const int l = tid & 63, w = tid >> 6;
  const int lr = l & 15, lg = l >> 4;

  // ---------------- P0: convert H fp32->bf16 + cos/sin table ----------------
  {
    const int n4 = (BB*SS*HIDD) >> 2, ncs = BB*SS*128;
    for (int i = gidx; i < n4 + ncs; i += gthr){
      if (i < n4){
        float4 v = ((const float4*)a.H)[i];
        ushort4 o; o.x=f2bf(v.x); o.y=f2bf(v.y); o.z=f2bf(v.z); o.w=f2bf(v.w);
        ((ushort4*)a.Hb)[i] = o;
      } else {
        int j = i - n4;
        int d = j & 127, bs = j >> 7;
        float p = (float)a.pos[bs];
        float inv = exp2f(-(float)(2*d) * (13.287712379549449f / 256.0f));
        float f = p * inv;
        a.cst[j] = make_float2(cosf(f), sinf(f));
      }
    }
  }
  // ---------------- P1: transpose-convert Wq/Wk/Wv/Wo ----------------
  {
    float (*t)[65] = reinterpret_cast<float(*)[65]>(smem);
    const int r = tid >> 4, c4 = (tid & 15) << 2;
    for (int z = bid; z < 2304; z += nblk){
      const float* W; ushort* dst; int N, rowOff, loc, nbx;
      if (z < 1024){ W=a.Wq; dst=a.Wt;  N=2048; rowOff=0;    loc=z;      nbx=32; }
      else if (z < 1152){ W=a.Wk; dst=a.Wt; N=256; rowOff=2048; loc=z-1024; nbx=4; }
      else if (z < 1280){ W=a.Wv; dst=a.Wt; N=256; rowOff=2304; loc=z-1152; nbx=4; }
      else { W=a.Wo; dst=a.Wot; N=2048; rowOff=0; loc=z-1280; nbx=32; }
      const int n0 = (loc % nbx) * 64, k0 = (loc / nbx) * 64;
      #pragma unroll
      for (int i2 = 0; i2 < 4; ++i2){
        int rr = r + i2*16;
        float4 v = *(const float4*)&W[(size_t)(k0 + rr) * N + n0 + c4];
        t[rr][c4] = v.x; t[rr][c4+1] = v.y; t[rr][c4+2] = v.z; t[rr][c4+3] = v.w;
      }
      __syncthreads();
      #pragma unroll
      for (int i2 = 0; i2 < 4; ++i2){
        int nn = r + i2*16;
        ushort4 o;
        o.x = f2bf(t[c4  ][nn]); o.y = f2bf(t[c4+1][nn]);
        o.z = f2bf(t[c4+2][nn]); o.w = f2bf(t[c4+3][nn]);
        *(ushort4*)&dst[(size_t)(rowOff + n0 + nn) * 2048 + k0 + c4] = o;
      }
      __syncthreads();
    }
  }
  gg.sync();
  // ---------------- P2: [Q|K|V] = Hb @ Wt^T (scatter epilogue) --------------
  gemm_phase(a.Hb, a.Wt, 20, 640, 64, 1, nullptr, a.Qr, a.Kr, a.Vr, smem, tid, bid, nblk);
  gg.sync();
  // ---------------- P3: transpose V + RoPE ----------------
  {
    ushort (*T)[72] = reinterpret_cast<ushort(*)[72]>(smem);
    for (int bidx = bid; bidx < 256; bidx += nblk){
      const int b = bidx >> 7, rest = bidx & 127;
      const int s0 = (rest >> 2) * 64, d0 = (rest & 3) * 64;
      #pragma unroll
      for (int i = 0; i < 2; ++i){
        int idx = i*256 + tid;
        int r = idx >> 3, c = (idx & 7) * 8;
        short8 v = *(const short8*)&a.Vr[((size_t)(b*SS) + s0 + r)*256 + d0 + c];
        #pragma unroll
        for (int j = 0; j < 8; ++j) T[r][c + j] = (ushort)v[j];
      }
      __syncthreads();
      #pragma unroll
      for (int i = 0; i < 2; ++i){
        int idx = i*256 + tid;
        int dr = idx >> 3, c = (idx & 7) * 8;
        short8 o;
        #pragma unroll
        for (int j = 0; j < 8; ++j) o[j] = (short)T[c + j][dr];
        *(short8*)&a.Vt[((size_t)(b*256) + d0 + dr)*2048 + s0 + c] = o;
      }
      __syncthreads();
    }
    const int NQ = BB*SS*NHH*128;
    for (int i = gidx; i < NQ + BB*SS*128; i += gthr){
      if (i < NQ){
        int d = i & 127, h = (i >> 7) & 7, bs = i >> 10;
        ushort* p = a.Qr + (size_t)bs*2048 + h*256 + d;
        float2 c = a.cst[bs*128 + d];
        float x1 = bf2f(p[0]), x2 = bf2f(p[128]);
        p[0]   = f2bf((x1*c.x - x2*c.y) * QSCALE);
        p[128] = f2bf((x2*c.x + x1*c.y) * QSCALE);
      } else {
        int j = i - NQ;
        int d = j & 127, bs = j >> 7;
        ushort* p = a.Kr + (size_t)bs*256 + d;
        float2 c = a.cst[bs*128 + d];
        float x1 = bf2f(p[0]), x2 = bf2f(p[128]);
        p[0]   = f2bf(x1*c.x - x2*c.y);
        p[128] = f2bf(x2*c.x + x1*c.y);
      }
    }
  }
  gg.sync();
  // ---------------- P4: softmax stats (online m,l), KVBLK=64, ksplit 4 ------
  {
    ushort* Ks = (ushort*)smem;                 // 64*256 = 32 KB
    for (int vt = bid; vt < 2048; vt += nblk){
      const int qt = vt & 31, ksp = (vt >> 5) & 3, bh = vt >> 7;
      const int b = bh >> 3, h = bh & 7;
      const int q0 = qt * 64;
      const int nkt = (q0 + 64) >> 6;
      const int per = (nkt + 3) >> 2;
      const int t0 = ksp * per;
      const int t1 = min(nkt, t0 + per);
      short8 qf[8];
      const ushort* qbase = a.Qr + ((size_t)(b*SS) + q0 + w*16 + lr) * 2048 + h*256;
      #pragma unroll
      for (int dc = 0; dc < 8; ++dc) qf[dc] = *(const short8*)&qbase[dc*32 + lg*8];
      float mrun[4], lrun[4];
      #pragma unroll
      for (int r = 0; r < 4; ++r){ mrun[r] = -3e38f; lrun[r] = 0.f; }
      for (int kt = t0; kt < t1; ++kt){
        const int k0 = kt * 64;
        #pragma unroll
        for (int t = 0; t < 8; ++t){
          int idx = t*256 + tid;
          int r = idx >> 5, g = idx & 31;
          int gl = g ^ (r & 7);                 // 512B-row swizzle
          gld_lds16(a.Kr + ((size_t)(b*SS) + k0 + r) * 256 + gl*8, Ks + (t*256 + (tid & ~63))*8);
        }
        __syncthreads();
        f32x4 sc[4] = {};
        #pragma unroll
        for (int j = 0; j < 4; ++j){
          const int krj = j*16 + lr;
          #pragma unroll
          for (int dc = 0; dc < 8; ++dc){
            short8 b8 = *(const short8*)&Ks[krj*256 + ((dc*32 + lg*8) ^ ((krj & 7) << 3))];
            sc[j] = mfma16(qf[dc], b8, sc[j]);
          }
        }
        __syncthreads();
        #pragma unroll
        for (int r = 0; r < 4; ++r){
          const int qq = q0 + w*16 + lg*4 + r;
          float s0 = (k0 + lr      <= qq) ? sc[0][r] : -3e38f;
          float s1 = (k0 + 16 + lr <= qq) ? sc[1][r] : -3e38f;
          float s2 = (k0 + 32 + lr <= qq) ? sc[2][r] : -3e38f;
          float s3 = (k0 + 48 + lr <= qq) ? sc[3][r] : -3e38f;
          float mx = fmaxf(fmaxf(s0, s1), fmaxf(s2, s3));
          #pragma unroll
          for (int d = 1; d < 16; d <<= 1) mx = fmaxf(mx, __shfl_xor(mx, d, 64));
          float mnew = fmaxf(mrun[r], mx);
          if (mnew > -1e37f){                    // uniform within 16-lane col group
            float ps = exp2f((s0 - mnew) * L2E) + exp2f((s1 - mnew) * L2E)
                     + exp2f((s2 - mnew) * L2E) + exp2f((s3 - mnew) * L2E);
            #pragma unroll
            for (int d = 1; d < 16; d <<= 1) ps += __shfl_xor(ps, d, 64);
            lrun[r] = lrun[r] * exp2f((mrun[r] - mnew) * L2E) + ps;
            mrun[r] = mnew;
          }
        }
      }
      if (lr == 0){
        #pragma unroll
        for (int r = 0; r < 4; ++r){
          int qq = q0 + w*16 + lg*4 + r;
          size_t sidx = (size_t)ksp * (BB*NHH*SS) + (size_t)bh * SS + qq;
          a.mpart[sidx] = mrun[r];
          a.lpart[sidx] = lrun[r];
        }
      }
    }
  }
  gg.sync();
  // ---------------- P5: merge k-split stats ----------------
  {
    const int N = BB*NHH*SS;
    for (int i = gidx; i < N; i += gthr){
      float m = -3e38f;
      #pragma unroll
      for (int s = 0; s < 4; ++s) m = fmaxf(m, a.mpart[s*N + i]);
      float lsum = 0.f;
      #pragma unroll
      for (int s = 0; s < 4; ++s){
        float ls = a.lpart[s*N + i];
        lsum += (ls > 0.f) ? ls * exp2f((a.mpart[s*N + i] - m) * L2E) : 0.f;
      }
      a.mfin[i] = m;
      a.invl[i] = 1.0f / lsum;
    }
  }
  gg.sync();
  // ---------------- P6: attn weights write + PV, KVBLK=64 ----------------
  {
    ushort* Ks = (ushort*)smem;      // [64][256] swz chunk^(r&7)   32 KB
    ushort* Vs = Ks + 64*256;        // [256][64] swz chunk^(r&7)   32 KB
    ushort* Ps = Vs + 256*64;        // [4][16*64] per-wave          8 KB
    for (int vt = bid; vt < 512; vt += nblk){
      const int qt = 31 - (vt & 31), bh = vt >> 5;
      const int b = bh >> 3, h = bh & 7;
      const int q0 = qt * 64;
      short8 qf[8];
      const ushort* qbase = a.Qr + ((size_t)(b*SS) + q0 + w*16 + lr) * 2048 + h*256;
      #pragma unroll
      for (int dc = 0; dc < 8; ++dc) qf[dc] = *(const short8*)&qbase[dc*32 + lg*8];
      float mrow[4], il[4];
      #pragma unroll
      for (int r = 0; r < 4; ++r){
        int qq = q0 + w*16 + lg*4 + r;
        mrow[r] = a.mfin[bh*SS + qq];
        il[r]   = a.invl[bh*SS + qq];
      }
      f32x4 oacc[16] = {};
      const int nkt = (q0 + 64) >> 6;
      for (int kt = 0; kt < nkt; ++kt){
        const int k0 = kt * 64;
        #pragma unroll
        for (int t = 0; t < 8; ++t){
          int idx = t*256 + tid;
          int r = idx >> 5, g = idx & 31;
          int gl = g ^ (r & 7);
          gld_lds16(a.Kr + ((size_t)(b*SS) + k0 + r) * 256 + gl*8, Ks + (t*256 + (tid & ~63))*8);
        }
        #pragma unroll
        for (int t = 0; t < 8; ++t){
          int idx = t*256 + tid;
          int r = idx >> 3, g = idx & 7;        // r = d-row of Vt tile (128B rows)
          int gl = g ^ (r & 7);
          gld_lds16(a.Vt + ((size_t)b*256 + r) * 2048 + k0 + gl*8, Vs + (t*256 + (tid & ~63))*8);
        }
        __syncthreads();
        f32x4 sc[4] = {};
        #pragma unroll
        for (int j = 0; j < 4; ++j){
          const int krj = j*16 + lr;
          #pragma unroll
          for (int dc = 0; dc < 8; ++dc){
            short8 b8 = *(const short8*)&Ks[krj*256 + ((dc*32 + lg*8) ^ ((krj & 7) << 3))];
            sc[j] = mfma16(qf[dc], b8, sc[j]);
          }
        }
        // p = exp(s - m); write attn = p/l; stash p (bf16, swizzled) for PV
        #pragma unroll
        for (int r = 0; r < 4; ++r){
          const int qq = q0 + w*16 + lg*4 + r;
          const int row = lg*4 + r;
          float* wrp = a.Wts + ((size_t)bh * SS + qq) * SS;
          #pragma unroll
          for (int j = 0; j < 4; ++j){
            const int kk = k0 + j*16 + lr;
            float p = (kk <= qq) ? exp2f((sc[j][r] - mrow[r]) * L2E) : 0.f;
            wrp[kk] = p * il[r];
            int chunk = j*2 + (lr >> 3);
            Ps[w*1024 + row*64 + ((chunk ^ (row & 7)) << 3) + (lr & 7)] = f2bf(p);
          }
        }
        // PV: out[16q][256d] += P[16q][64k] x V[64k][256d] (wave-local Ps)
        #pragma unroll
        for (int kc = 0; kc < 2; ++kc){
          short8 pa = *(const short8*)&Ps[w*1024 + lr*64 + (((kc*4 + lg) ^ (lr & 7)) << 3)];
          #pragma unroll
          for (int nf = 0; nf < 16; ++nf){
            int dr = nf*16 + lr;
            short8 vb = *(const short8*)&Vs[dr*64 + (((kc*4 + lg) ^ (dr & 7)) << 3)];
            oacc[nf] = mfma16(pa, vb, oacc[nf]);
          }
        }
        __syncthreads();
      }
      // zero-fill strictly-above-block columns (exact zeros in reference too)
      const int zc0 = q0 + 64;
      if (zc0 < SS){
        const int quads = (SS - zc0) >> 2;
        const float4 z4 = make_float4(0.f, 0.f, 0.f, 0.f);
        for (int rr = w; rr < 64; rr += 4){
          float* rowp = a.Wts + ((size_t)bh*SS + q0 + rr)*SS + zc0;
          for (int c = l; c < quads; c += 64)
            *(float4*)&rowp[c*4] = z4;
        }
      }
      // write PV result (scaled by 1/l) as bf16 rows (b,s) x cols h*256+d
      #pragma unroll
      for (int nf = 0; nf < 16; ++nf){
        #pragma unroll
        for (int r = 0; r < 4; ++r){
          int qq = q0 + w*16 + lg*4 + r;
          int d  = nf*16 + lr;
          a.Ows[((size_t)(b*SS) + qq)*2048 + h*256 + d] = f2bf(oacc[nf][r] * il[r]);
        }
      }
    }
  }
  gg.sync();
  // ---------------- P7: attn_output = Ows @ Wot^T ----------------
  gemm_phase(a.Ows, a.Wot, 16, 512, 64, 0, a.out, nullptr, nullptr, nullptr, smem, tid, bid, nblk);
}

// ---------------- host launch ----------------
extern "C" void kernel_launch(void* const* d_in, const int* in_sizes, int n_in,
                              void* d_out, int out_size, void* d_ws, size_t ws_size,
                              hipStream_t stream){
  const float* H  = (const float*)d_in[0];
  const int*  pos = (const int*)d_in[2];
  const float* Wq = (const float*)d_in[3];
  const float* Wk = (const float*)d_in[4];
  const float* Wv = (const float*)d_in[5];
  const float* Wo = (const float*)d_in[6];
  float* out = (float*)d_out;
  float* Wts = out + (size_t)BB*SS*HIDD;          // attn_weights region (also early scratch)

  // Scratch inside the (later fully overwritten) weights region: Hb 16.8MB + Wt 10.5MB
  ushort* Hb = (ushort*)Wts;
  ushort* Wt = Hb + (size_t)BB*SS*HIDD;

  char* ws = (char*)d_ws;
  size_t off = 0;
  auto alloc = [&](size_t bytes)->char*{
    char* p = ws + off; off += (bytes + 255) & ~(size_t)255; return p;
  };
  ushort* Wot   = (ushort*)alloc((size_t)2048*2048*2);
  ushort* Qr    = (ushort*)alloc((size_t)BB*SS*NHH*HDD*2);
  ushort* Kr    = (ushort*)alloc((size_t)BB*SS*HDD*2);
  ushort* Vr    = (ushort*)alloc((size_t)BB*SS*HDD*2);
  ushort* Vt    = (ushort*)alloc((size_t)BB*HDD*SS*2);
  float2* cst   = (float2*)alloc((size_t)BB*SS*128*8);
  float*  mpart = (float*)alloc((size_t)4*BB*NHH*SS*4);
  float*  lpart = (float*)alloc((size_t)4*BB*NHH*SS*4);
  float*  mfin  = (float*)alloc((size_t)BB*NHH*SS*4);
  float*  invl  = (float*)alloc((size_t)BB*NHH*SS*4);
  ushort* Ows   = (ushort*)alloc((size_t)BB*SS*NHH*HDD*2);
  (void)ws_size; (void)in_sizes; (void)n_in; (void)out_size;

  KArgs args;
  args.H = H; args.pos = pos;
  args.Wq = Wq; args.Wk = Wk; args.Wv = Wv; args.Wo = Wo;
  args.out = out; args.Wts = Wts;
  args.Hb = Hb; args.Wt = Wt; args.Wot = Wot;
  args.Qr = Qr; args.Kr = Kr; args.Vr = Vr; args.Vt = Vt;
  args.cst = cst;
  args.mpart = mpart; args.lpart = lpart; args.mfin = mfin; args.invl = invl;
  args.Ows = Ows;

  int occ = 0;
  hipOccupancyMaxActiveBlocksPerMultiprocessor(&occ, k_fused, 256, 0);
  int grid = (occ >= 2) ? 512 : 256;   // 72 KB LDS -> expect 2 blocks/CU
  void* kp[] = { (void*)&args };
  hipLaunchCooperativeKernel(k_fused, dim3(grid), dim3(256), kp, 0, stream);
}